// Round 1
// baseline (266.983 us; speedup 1.0000x reference)
//
#include <hip/hip_runtime.h>
#include <math.h>

#define CB 8      // c8 = C/8 (q,k channels)
#define CC 64     // C
#define HH 256
#define WW 256

// One thread per pixel. Lane layout: t = w*4 + r  (r = row within 4-row block,
// w = column within the block's 64-column span). Each 16-lane group is a 4x4
// spatial patch: horizontal attention = 4-lane quad shuffles, vertical
// attention = 16-lane group shuffles. Zero LDS, zero workspace.
__global__ __launch_bounds__(256) void area_attn_kernel(
    const float* __restrict__ x,
    const float* __restrict__ Wq, const float* __restrict__ bq,
    const float* __restrict__ Wk, const float* __restrict__ bk,
    const float* __restrict__ Wv, const float* __restrict__ bv,
    const float* __restrict__ gamma,
    float* __restrict__ out)
{
    const int t = threadIdx.x;
    const int r = t & 3;          // row within 4-row block
    const int w = t >> 2;         // 0..63 column within tile
    const int wg = blockIdx.x * 64 + w;   // global column
    const int h  = blockIdx.y * 4 + r;    // global row
    const int b  = blockIdx.z;

    const size_t HW  = (size_t)HH * WW;
    const size_t pix = (size_t)b * CC * HW + (size_t)h * WW + wg;

    // ---------------- 1x1 conv: q (8), k (8), v (64) for my pixel ----------------
    float vq[CB], vk[CB], vv[CC];
#pragma unroll
    for (int o = 0; o < CB; ++o) { vq[o] = bq[o]; vk[o] = bk[o]; }
#pragma unroll
    for (int o = 0; o < CC; ++o) vv[o] = bv[o];

#pragma unroll 4
    for (int c = 0; c < CC; ++c) {
        const float xv = x[pix + (size_t)c * HW];
#pragma unroll
        for (int o = 0; o < CB; ++o) {
            vq[o] = fmaf(xv, Wq[o * CC + c], vq[o]);
            vk[o] = fmaf(xv, Wk[o * CC + c], vk[o]);
        }
#pragma unroll
        for (int o = 0; o < CC; ++o) {
            vv[o] = fmaf(xv, Wv[o * CC + c], vv[o]);
        }
    }

    // ---------------- horizontal scores: S[j] = q(me) . k(row j, same col) -------
    // My thread is query row i = r. Softmax over keys j is thread-local.
    float Ah[4];
    {
        float S[4];
#pragma unroll
        for (int j = 0; j < 4; ++j) {
            float s = 0.f;
#pragma unroll
            for (int c = 0; c < CB; ++c) {
                float kc = __shfl(vk[c], j, 4);   // row j within my quad
                s = fmaf(vq[c], kc, s);
            }
            S[j] = s;
        }
        float m  = fmaxf(fmaxf(S[0], S[1]), fmaxf(S[2], S[3]));
        float e0 = __expf(S[0] - m), e1 = __expf(S[1] - m);
        float e2 = __expf(S[2] - m), e3 = __expf(S[3] - m);
        float inv = 1.f / (e0 + e1 + e2 + e3);
        Ah[0] = e0 * inv; Ah[1] = e1 * inv; Ah[2] = e2 * inv; Ah[3] = e3 * inv;
    }

    // ---------------- vertical scores: S[j] = q(me) . k(col j, same row) --------
    // My thread is query col i = (w & 3) within its 4-col block.
    float Av[4];
    {
        float S[4];
#pragma unroll
        for (int j = 0; j < 4; ++j) {
            float s = 0.f;
#pragma unroll
            for (int c = 0; c < CB; ++c) {
                float kc = __shfl(vk[c], (j << 2) | r, 16);  // col j, my row
                s = fmaf(vq[c], kc, s);
            }
            S[j] = s;
        }
        float m  = fmaxf(fmaxf(S[0], S[1]), fmaxf(S[2], S[3]));
        float e0 = __expf(S[0] - m), e1 = __expf(S[1] - m);
        float e2 = __expf(S[2] - m), e3 = __expf(S[3] - m);
        float inv = 1.f / (e0 + e1 + e2 + e3);
        Av[0] = e0 * inv; Av[1] = e1 * inv; Av[2] = e2 * inv; Av[3] = e3 * inv;
    }

    // ---------------- exchange attention columns -------------------------------
    // Output at key index j: out[:, j] = sum_i V[:, i] * A[i, j]
    // I am output j = r (horizontal) / j = w&3 (vertical); need column j of A,
    // i.e. A[i][j_me] from each provider i.
    const int jc = w & 3;
    float ah[4] = {0.f, 0.f, 0.f, 0.f};
    float av[4] = {0.f, 0.f, 0.f, 0.f};
#pragma unroll
    for (int j = 0; j < 4; ++j) {
#pragma unroll
        for (int i = 0; i < 4; ++i) {
            float th = __shfl(Ah[j], i, 4);               // A_h[i][j]
            float tv = __shfl(Av[j], (i << 2) | r, 16);   // A_v[i][j]
            if (j == r)  ah[i] = th;
            if (j == jc) av[i] = tv;
        }
    }

    // ---------------- PV: acc[c] = sum_i ah[i]*v(row i) + sum_i av[i]*v(col i) --
    float acc[CC];
#pragma unroll
    for (int c = 0; c < CC; ++c) acc[c] = 0.f;

#pragma unroll
    for (int i = 0; i < 4; ++i) {
#pragma unroll
        for (int c = 0; c < CC; ++c) {
            float vh = __shfl(vv[c], i, 4);               // v at row i, my col
            acc[c] = fmaf(ah[i], vh, acc[c]);
        }
    }
#pragma unroll
    for (int i = 0; i < 4; ++i) {
#pragma unroll
        for (int c = 0; c < CC; ++c) {
            float vV = __shfl(vv[c], (i << 2) | r, 16);   // v at col i, my row
            acc[c] = fmaf(av[i], vV, acc[c]);
        }
    }

    // ---------------- epilogue: out = gamma*(h_out + v_out) + x ----------------
    const float g = gamma[0];
#pragma unroll 8
    for (int c = 0; c < CC; ++c) {
        out[pix + (size_t)c * HW] = fmaf(g, acc[c], x[pix + (size_t)c * HW]);
    }
}

extern "C" void kernel_launch(void* const* d_in, const int* in_sizes, int n_in,
                              void* d_out, int out_size, void* d_ws, size_t ws_size,
                              hipStream_t stream) {
    const float* x     = (const float*)d_in[0];
    const float* Wq    = (const float*)d_in[1];
    const float* bq    = (const float*)d_in[2];
    const float* Wk    = (const float*)d_in[3];
    const float* bk    = (const float*)d_in[4];
    const float* Wv    = (const float*)d_in[5];
    const float* bv    = (const float*)d_in[6];
    const float* gamma = (const float*)d_in[7];
    float* out = (float*)d_out;

    dim3 grid(WW / 64, HH / 4, 8);   // (4, 64, 8)
    area_attn_kernel<<<grid, 256, 0, stream>>>(x, Wq, bq, Wk, bk, Wv, bv, gamma, out);
}

// Round 2
// 141.343 us; speedup vs baseline: 1.8889x; 1.8889x over previous
//
#include <hip/hip_runtime.h>
#include <math.h>

#define CB 8      // q,k channels
#define CC 64     // C
#define HH 256
#define WW 256

// Lane map: w = t&63 (column within 64-col tile, consecutive lanes = consecutive
// columns -> perfectly coalesced global access), r = t>>6 (row: wave id, 4 waves).
// Horizontal attention mixes rows -> cross-wave via LDS.
// Vertical attention mixes columns within 4-col blocks -> LDS broadcast reads.
//
// LDS layouts (all conflict-free: readers/writers access consecutive w per instr):
//   k_lds [c<8][row<4][w<64]              8 KB
//   ah4   [row i<4][w<64]  (float4 over j) 4 KB   (A_h[i][j] written by row-i thread)
//   av4   [row r<4][w<64]  (float4 over j) 4 KB   (A_v row for col-block of w)
//   v_lds [buf<2][cc<4][row<4][w<64]       8 KB   (double-buffered 4-channel chunk)
__global__ __launch_bounds__(256) void area_attn_kernel(
    const float* __restrict__ x,
    const float* __restrict__ Wq, const float* __restrict__ bq,
    const float* __restrict__ Wk, const float* __restrict__ bk,
    const float* __restrict__ Wv, const float* __restrict__ bv,
    const float* __restrict__ gamma,
    float* __restrict__ out)
{
    __shared__ float  k_lds[8 * 4 * 64];
    __shared__ float4 ah4[4 * 64];
    __shared__ float4 av4[4 * 64];
    __shared__ float  v_lds[2 * 4 * 4 * 64];

    const int t  = threadIdx.x;
    const int w  = t & 63;        // column within tile
    const int r  = t >> 6;        // row within 4-row block (= wave id)
    const int jc = w & 3;         // my column index within 4-col block
    const int wb = w & ~3;        // base of my 4-col block

    const int wg = blockIdx.x * 64 + w;
    const int h  = blockIdx.y * 4 + r;
    const int b  = blockIdx.z;

    const size_t HW  = (size_t)HH * WW;
    const size_t pix = (size_t)b * CC * HW + (size_t)h * WW + wg;

    // ---- load my pixel's 64 channels (coalesced: lanes = consecutive w) ----
    float xr[CC];
#pragma unroll
    for (int c = 0; c < CC; ++c) xr[c] = x[pix + (size_t)c * HW];

    // ---- q,k conv (8 ch each) ----
    float vq[CB], vk[CB];
#pragma unroll
    for (int o = 0; o < CB; ++o) { vq[o] = bq[o]; vk[o] = bk[o]; }
#pragma unroll
    for (int c = 0; c < CC; ++c) {
        const float xv = xr[c];
#pragma unroll
        for (int o = 0; o < CB; ++o) {
            vq[o] = fmaf(xv, Wq[o * CC + c], vq[o]);
            vk[o] = fmaf(xv, Wk[o * CC + c], vk[o]);
        }
    }

    // publish k: k_lds[c][r][w]
#pragma unroll
    for (int c = 0; c < CB; ++c) k_lds[c * 256 + r * 64 + w] = vk[c];
    __syncthreads();

    // ---- horizontal scores: I am query row r; S[j] = q(me) . k(row j, col w) ----
    {
        float S[4];
#pragma unroll
        for (int j = 0; j < 4; ++j) {
            float s = 0.f;
#pragma unroll
            for (int c = 0; c < CB; ++c)
                s = fmaf(vq[c], k_lds[c * 256 + j * 64 + w], s);
            S[j] = s;
        }
        float m  = fmaxf(fmaxf(S[0], S[1]), fmaxf(S[2], S[3]));
        float e0 = __expf(S[0] - m), e1 = __expf(S[1] - m);
        float e2 = __expf(S[2] - m), e3 = __expf(S[3] - m);
        float inv = 1.f / (e0 + e1 + e2 + e3);
        ah4[r * 64 + w] = make_float4(e0 * inv, e1 * inv, e2 * inv, e3 * inv);
    }

    // ---- vertical scores: I am query col jc; S[j] = q(me) . k(row r, col wb|j) ----
    {
        float S[4];
#pragma unroll
        for (int j = 0; j < 4; ++j) {
            float s = 0.f;
#pragma unroll
            for (int c = 0; c < CB; ++c)
                s = fmaf(vq[c], k_lds[c * 256 + r * 64 + (wb | j)], s);
            S[j] = s;
        }
        float m  = fmaxf(fmaxf(S[0], S[1]), fmaxf(S[2], S[3]));
        float e0 = __expf(S[0] - m), e1 = __expf(S[1] - m);
        float e2 = __expf(S[2] - m), e3 = __expf(S[3] - m);
        float inv = 1.f / (e0 + e1 + e2 + e3);
        av4[r * 64 + w] = make_float4(e0 * inv, e1 * inv, e2 * inv, e3 * inv);
    }
    __syncthreads();

    // ---- gather the A-columns I need as output index ----
    // h: out col j = r  -> need A_h[i][r] from row-i threads (same w)
    // v: out col j = jc -> need A_v[i][jc] from threads at col wb|i (same row)
    float ahc[4], avc[4];
#pragma unroll
    for (int i = 0; i < 4; ++i) {
        ahc[i] = ((const float*)&ah4[i * 64 + w])[r];
        avc[i] = ((const float*)&av4[r * 64 + (wb | i)])[jc];
    }

    const float g = gamma[0];

    // ---- v conv + PV + epilogue, chunked 4 channels at a time ----
    for (int cb = 0; cb < 16; ++cb) {
        const int p = (cb & 1) * 1024;

        // conv: 4 v-channels for my pixel
        float v4[4];
#pragma unroll
        for (int j = 0; j < 4; ++j) {
            const int o = cb * 4 + j;
            float s = bv[o];
#pragma unroll
            for (int c = 0; c < CC; ++c)
                s = fmaf(xr[c], Wv[o * CC + c], s);
            v4[j] = s;
        }

        // publish chunk: v_lds[p][cc][row][w]
#pragma unroll
        for (int j = 0; j < 4; ++j) v_lds[p + j * 256 + r * 64 + w] = v4[j];
        __syncthreads();

        // PV: out[c] = sum_i A_h[i][r] * v(row i, col w)
        //            + sum_i A_v[i][jc] * v(row r, col wb|i)
        float o4[4] = {0.f, 0.f, 0.f, 0.f};
#pragma unroll
        for (int i = 0; i < 4; ++i) {
#pragma unroll
            for (int j = 0; j < 4; ++j) {
                o4[j] = fmaf(ahc[i], v_lds[p + j * 256 + i * 64 + w], o4[j]);
                o4[j] = fmaf(avc[i], v_lds[p + j * 256 + r * 64 + (wb | i)], o4[j]);
            }
        }

        // epilogue: out = gamma*(h+v) + x   (coalesced stores)
#pragma unroll
        for (int j = 0; j < 4; ++j) {
            const int o = cb * 4 + j;
            out[pix + (size_t)o * HW] = fmaf(g, o4[j], xr[o]);
        }
    }
}

extern "C" void kernel_launch(void* const* d_in, const int* in_sizes, int n_in,
                              void* d_out, int out_size, void* d_ws, size_t ws_size,
                              hipStream_t stream) {
    const float* x     = (const float*)d_in[0];
    const float* Wq    = (const float*)d_in[1];
    const float* bq    = (const float*)d_in[2];
    const float* Wk    = (const float*)d_in[3];
    const float* bk    = (const float*)d_in[4];
    const float* Wv    = (const float*)d_in[5];
    const float* bv    = (const float*)d_in[6];
    const float* gamma = (const float*)d_in[7];
    float* out = (float*)d_out;

    dim3 grid(WW / 64, HH / 4, 8);   // (4, 64, 8)
    area_attn_kernel<<<grid, 256, 0, stream>>>(x, Wq, bq, Wk, bk, Wv, bv, gamma, out);
}